// Round 24
// baseline (112.565 us; speedup 1.0000x reference)
//
#include <hip/hip_runtime.h>

typedef float    f32x4  __attribute__((ext_vector_type(4)));
typedef _Float16 half8  __attribute__((ext_vector_type(8)));
typedef _Float16 half4v __attribute__((ext_vector_type(4)));

#define MFMA16(a,b,c) __builtin_amdgcn_mfma_f32_16x16x32_f16(a,b,c,0,0,0)

__device__ __forceinline__ float exp2_fast(float x){
  float y; asm("v_exp_f32 %0, %1" : "=v"(y) : "v"(x)); return y;
}
// async global->LDS, 16B per lane; LDS dest is wave-uniform base + lane*16
__device__ __forceinline__ void gload_lds16(const _Float16* g, _Float16* l){
  __builtin_amdgcn_global_load_lds(
      (const __attribute__((address_space(1))) unsigned int*)(g),
      (__attribute__((address_space(3))) unsigned int*)(l),
      16, 0, 0);
}

#define S_LEN 2048
#define E_DIM 1024
#define H_NUM 16
#define D_DIM 64
#define NBH   32
#define M_ROWS 4096
#define N3    3072
#define LOG2E 1.44269504089f

// ---------------- fused prep: X cast + Wqkv^T + Wo^T in one dispatch --------
__global__ __launch_bounds__(256) void prep_kernel(
    const float* __restrict__ X, const float* __restrict__ Wqkv,
    const float* __restrict__ Wo,
    _Float16* __restrict__ Xh, _Float16* __restrict__ Wqh,
    _Float16* __restrict__ Woh)
{
  __shared__ float tile[32][33];
  const int blk = blockIdx.x, tid = threadIdx.x;
  if (blk < 4096){
    const int i = blk * 256 + tid;                  // i < 4096*256 = ME/4
    const float4 v = reinterpret_cast<const float4*>(X)[i];
    half4v h;
    h[0] = (_Float16)v.x; h[1] = (_Float16)v.y;
    h[2] = (_Float16)v.z; h[3] = (_Float16)v.w;
    *reinterpret_cast<half4v*>(&Xh[(size_t)i*4]) = h;
    return;
  }
  const float* in; _Float16* out; int R, C, bx, by;
  if (blk < 4096 + 3072){
    const int b2 = blk - 4096;
    in = Wqkv; out = Wqh; R = E_DIM; C = N3;
    bx = (b2 % 96) * 32; by = (b2 / 96) * 32;
  } else {
    const int b2 = blk - 7168;
    in = Wo; out = Woh; R = E_DIM; C = E_DIM;
    bx = (b2 % 32) * 32; by = (b2 / 32) * 32;
  }
  const int tx = tid & 31, ty = tid >> 5;           // 256 threads = 32x8
#pragma unroll
  for (int i = ty; i < 32; i += 8)
    tile[i][tx] = in[(size_t)(by + i) * C + bx + tx];
  __syncthreads();
#pragma unroll
  for (int i = ty; i < 32; i += 8)
    out[(size_t)(bx + i) * R + by + tx] = (_Float16)tile[tx][i];
}

// ---------------- fp16 GEMM (m97 structure + T2 swizzle), 128x128 ----------
// T1 XCD-chunked block remap: each XCD gets a contiguous run of block ids
// (4 m-rows x all n-tiles for GEMM1) so its A-panels stay L2-resident.
template<int EPI>
__global__ __launch_bounds__(256, 3) void gemm97(
    const _Float16* __restrict__ A, const _Float16* __restrict__ B,
    int Kdim, int Ndim, float* __restrict__ Cout,
    _Float16* __restrict__ qh, _Float16* __restrict__ kh, _Float16* __restrict__ vh)
{
  __shared__ __align__(16) _Float16 sA[128][64], sB[128][64];
  const int tid = threadIdx.x;
  const int nx = gridDim.x, nwg = nx * gridDim.y;
  int bidx = blockIdx.x, bidy = blockIdx.y;
  if ((nwg & 7) == 0){
    const int id = bidx + nx * bidy;
    const int nid = (id & 7) * (nwg >> 3) + (id >> 3);   // bijective: nwg%8==0
    bidx = nid % nx; bidy = nid / nx;
  }
  const int m0 = bidy * 128, n0 = bidx * 128;
  const int wid = tid >> 6, lane = tid & 63;
  const int wr = (wid >> 1) * 64, wc = (wid & 1) * 64;
  const int lr = lane & 15, lc = lane >> 4;
  const int ldrow = lane >> 3;                        // 0..7 within chunk
  const int ldcol = ((lane & 7) ^ ldrow) * 8;         // inverse-swizzled source col
  const int swz = (lr & 7) << 4;                      // byte XOR for reads

  f32x4 acc[4][4] = {};
  const int nK = Kdim >> 6;
  for (int ks = 0; ks < nK; ++ks){
    const int k0 = ks << 6;
#pragma unroll
    for (int cc = 0; cc < 4; ++cc){
      const int c = wid * 4 + cc;
      const int row = c * 8 + ldrow;
      gload_lds16(&A[(size_t)(m0 + row) * Kdim + k0 + ldcol], &sA[c*8][0]);
      gload_lds16(&B[(size_t)(n0 + row) * Kdim + k0 + ldcol], &sB[c*8][0]);
    }
    __syncthreads();
    const char* ab = (const char*)&sA[0][0];
    const char* bb = (const char*)&sB[0][0];
#pragma unroll
    for (int kk = 0; kk < 64; kk += 32){
      half8 fa[4], fb[4];
#pragma unroll
      for (int t = 0; t < 4; ++t){
        fa[t] = *reinterpret_cast<const half8*>(
            ab + (wr + t*16 + lr)*128 + ((kk*2 + lc*16) ^ swz));
        fb[t] = *reinterpret_cast<const half8*>(
            bb + (wc + t*16 + lr)*128 + ((kk*2 + lc*16) ^ swz));
      }
#pragma unroll
      for (int mt = 0; mt < 4; ++mt)
#pragma unroll
        for (int nt = 0; nt < 4; ++nt)
          acc[mt][nt] = MFMA16(fa[mt], fb[nt], acc[mt][nt]);
    }
    __syncthreads();
  }
#pragma unroll
  for (int mt = 0; mt < 4; ++mt)
#pragma unroll
    for (int nt = 0; nt < 4; ++nt)
#pragma unroll
      for (int r = 0; r < 4; ++r){
        const int m = m0 + wr + mt*16 + lc*4 + r;
        const int n = n0 + wc + nt*16 + lr;
        float v = acc[mt][nt][r];
        if (EPI == 0){
          Cout[(size_t)m * Ndim + n] = v;
        } else {
          const int t = n >> 10, rem = n & 1023, hh = rem >> 6, d = rem & 63;
          const int b = m >> 11, s = m & 2047;
          const int bh = b * H_NUM + hh;
          if (t == 0) v *= (0.125f * LOG2E);  // fold 1/sqrt(64) and log2(e) into Q
          size_t o;
          if (t == 2)  o = ((size_t)bh * D_DIM + d) * S_LEN + s;   // V transposed
          else         o = ((size_t)bh * S_LEN + s) * D_DIM + d;
          _Float16* ph = (t == 0) ? qh : (t == 1) ? kh : vh;
          ph[o] = (_Float16)v;
        }
      }
}

// ---------------- fp16 GEMM, 64x128 tile (occupancy variant for GEMM2) -----
// T1 XCD-chunked remap: Wo^T (2MB) becomes L2-resident per XCD.
__global__ __launch_bounds__(256, 4) void gemm64(
    const _Float16* __restrict__ A, const _Float16* __restrict__ B,
    int Kdim, int Ndim, float* __restrict__ Cout)
{
  __shared__ __align__(16) _Float16 sA[64][64], sB[128][64];
  const int tid = threadIdx.x;
  const int nx = gridDim.x, nwg = nx * gridDim.y;
  int bidx = blockIdx.x, bidy = blockIdx.y;
  if ((nwg & 7) == 0){
    const int id = bidx + nx * bidy;
    const int nid = (id & 7) * (nwg >> 3) + (id >> 3);   // bijective: nwg%8==0
    bidx = nid % nx; bidy = nid / nx;
  }
  const int m0 = bidy * 64, n0 = bidx * 128;
  const int wid = tid >> 6, lane = tid & 63;
  const int wr = (wid >> 1) * 32, wc = (wid & 1) * 64;
  const int lr = lane & 15, lc = lane >> 4;
  const int ldrow = lane >> 3;
  const int ldcol = ((lane & 7) ^ ldrow) * 8;
  const int swz = (lr & 7) << 4;

  f32x4 acc[2][4] = {};
  const int nK = Kdim >> 6;
  for (int ks = 0; ks < nK; ++ks){
    const int k0 = ks << 6;
#pragma unroll
    for (int cc = 0; cc < 2; ++cc){
      const int c = wid * 2 + cc;
      const int row = c * 8 + ldrow;
      gload_lds16(&A[(size_t)(m0 + row) * Kdim + k0 + ldcol], &sA[c*8][0]);
    }
#pragma unroll
    for (int cc = 0; cc < 4; ++cc){
      const int c = wid * 4 + cc;
      const int row = c * 8 + ldrow;
      gload_lds16(&B[(size_t)(n0 + row) * Kdim + k0 + ldcol], &sB[c*8][0]);
    }
    __syncthreads();
    const char* ab = (const char*)&sA[0][0];
    const char* bb = (const char*)&sB[0][0];
#pragma unroll
    for (int kk = 0; kk < 64; kk += 32){
      half8 fa[2], fb[4];
#pragma unroll
      for (int t = 0; t < 2; ++t)
        fa[t] = *reinterpret_cast<const half8*>(
            ab + (wr + t*16 + lr)*128 + ((kk*2 + lc*16) ^ swz));
#pragma unroll
      for (int t = 0; t < 4; ++t)
        fb[t] = *reinterpret_cast<const half8*>(
            bb + (wc + t*16 + lr)*128 + ((kk*2 + lc*16) ^ swz));
#pragma unroll
      for (int mt = 0; mt < 2; ++mt)
#pragma unroll
        for (int nt = 0; nt < 4; ++nt)
          acc[mt][nt] = MFMA16(fa[mt], fb[nt], acc[mt][nt]);
    }
    __syncthreads();
  }
#pragma unroll
  for (int mt = 0; mt < 2; ++mt)
#pragma unroll
    for (int nt = 0; nt < 4; ++nt)
#pragma unroll
      for (int r = 0; r < 4; ++r){
        const int m = m0 + wr + mt*16 + lc*4 + r;
        const int n = n0 + wc + nt*16 + lr;
        Cout[(size_t)m * Ndim + n] = acc[mt][nt][r];
      }
}

// ---------------- flash attention, KV-split partial, 6 blocks/CU -------------
// 2048 blocks: (bh, qt, half), <=16 iters each. LDS = 24576 B -> 6 blocks/CU.
// Split-drain staging (T4): issue K-DMAs then V-DMAs; QK waits only on K
// (vmcnt(2) + raw barrier); V's latency hides under QK+softmax; PV waits
// vmcnt(0) + raw barrier. One extra barrier, ~400cy less exposed drain.
__global__ __launch_bounds__(256, 6) void attn_partial(
    const _Float16* __restrict__ Qh, const _Float16* __restrict__ Kh,
    const _Float16* __restrict__ Vth,
    _Float16* __restrict__ Opart, float* __restrict__ Spart)
{
  __shared__ __align__(16) _Float16 sK[64][64];      // 8192 B [kv][d]
  __shared__ __align__(16) _Float16 sV[64][64];      // 8192 B [d][kv]
  __shared__ __align__(16) _Float16 sP[4][16][64];   // 8192 B per-wave P
  const int tid = threadIdx.x, wid = tid >> 6, lane = tid & 63;
  const int id  = blockIdx.x;                  // 0..2047
  const int xcd = id & 7, seq = id >> 3;       // seq 0..255
  const int bh  = xcd + 8 * (seq & 3);
  const int rest = seq >> 2;                   // 0..63
  const int qt  = 31 - (rest >> 1);            // long blocks dispatch first
  const int half = rest & 1;
  const int h0 = (qt + 1) >> 1;
  const int t0 = half ? h0 : 0;
  const int t1 = half ? (qt + 1) : h0;
  const int q0 = qt * 64;
  const int lr = lane & 15, lc = lane >> 4;
  const int swz = (lr & 7) << 4;               // byte XOR for swizzled LDS accesses
  const size_t base = (size_t)bh * S_LEN * D_DIM;

  const int pidx = (bh * 32 + qt) * 2 + half;
  _Float16* Op = Opart + (size_t)pidx * 4096;
  float*    Sp = Spart + (size_t)pidx * 192;   // [3][64]

  if (t1 <= t0){                               // empty chunk (qt=0, half0)
#pragma unroll
    for (int dt = 0; dt < 4; ++dt)
#pragma unroll
      for (int r = 0; r < 4; ++r)
        Op[(wid*16 + lc*4 + r)*64 + dt*16 + lr] = (_Float16)0.f;
    if (lane < 16){
      Sp[wid*16 + lr] = -1e30f;
      Sp[64 + wid*16 + lr] = 0.f;
      Sp[128 + wid*16 + lr] = -1e30f;
    }
    return;
  }

  // staging geometry: wave w stages chunks {2w,2w+1} (8 rows each)
  const int lrow = lane >> 3;                       // 0..7
  const int cswz = ((lane & 7) ^ lrow) * 8;         // inverse-swizzled source col

  // issue K loads FIRST (oldest), then V: vmcnt(2) waits exactly for K.
  auto stageK = [&](int t){
    const int kv0 = t * 64;
#pragma unroll
    for (int cc = 0; cc < 2; ++cc){
      const int ch = wid * 2 + cc;
      const int row = ch * 8 + lrow;
      gload_lds16(&Kh[base + (size_t)(kv0 + row) * D_DIM + cswz], &sK[ch*8][0]);
    }
  };
  auto stageV = [&](int t){
    const int kv0 = t * 64;
#pragma unroll
    for (int cc = 0; cc < 2; ++cc){
      const int ch = wid * 2 + cc;
      const int row = ch * 8 + lrow;
      gload_lds16(&Vth[base + (size_t)row * S_LEN + kv0 + cswz], &sV[ch*8][0]);
    }
  };

  // Q fragments (B-operand), hoisted; Q already scaled by log2e/8
  half8 fq[2];
  {
    const int qrow = q0 + wid*16 + lr;
#pragma unroll
    for (int kc = 0; kc < 2; ++kc)
      fq[kc] = *reinterpret_cast<const half8*>(&Qh[base + (size_t)qrow * 64 + kc*32 + lc*8]);
  }

  f32x4 acc[4] = {};
  float m = -1e30f, l = 0.f, tm = -1e30f;   // per-lane stats for q = lr

#pragma unroll 1
  for (int t = t0; t < t1; ++t){
    __syncthreads();                        // prior iteration's LDS reads done
    stageK(t);                              // 2 K-DMAs (oldest)
    stageV(t);                              // 2 V-DMAs (newest)
    asm volatile("s_waitcnt vmcnt(2)" ::: "memory");   // own K landed
    __builtin_amdgcn_sched_barrier(0);
    __builtin_amdgcn_s_barrier();           // all waves' K visible; V in flight

    // ST = K·Q^T: lane holds q=lr (col), k = nt*16 + lc*4 + r (row)
    const char* kb = (const char*)&sK[0][0];
    f32x4 sc[4];
    __builtin_amdgcn_s_setprio(1);
#pragma unroll
    for (int nt = 0; nt < 4; ++nt){
      f32x4 z = {};
#pragma unroll
      for (int kc = 0; kc < 2; ++kc){
        const half8 fk = *reinterpret_cast<const half8*>(
            kb + (nt*16 + lr)*128 + ((kc*64 + lc*16) ^ swz));
        z = MFMA16(fk, fq[kc], z);
      }
      sc[nt] = z;
    }
    __builtin_amdgcn_s_setprio(0);

    if (t == qt){   // diagonal: mask k > q
#pragma unroll
      for (int nt = 0; nt < 4; ++nt)
#pragma unroll
        for (int r = 0; r < 4; ++r)
          if (nt*16 + lc*4 + r > wid*16 + lr) sc[nt][r] = -1e30f;
    }

    // in-lane max over 16 + 2 cross-lane hops (lanes lr, lr+16, lr+32, lr+48)
    f32x4 a;
#pragma unroll
    for (int j = 0; j < 4; ++j)
      a[j] = fmaxf(fmaxf(sc[0][j], sc[1][j]), fmaxf(sc[2][j], sc[3][j]));
    float mx = fmaxf(fmaxf(a[0], a[1]), fmaxf(a[2], a[3]));
    mx = fmaxf(mx, __shfl_xor(mx, 16));
    mx = fmaxf(mx, __shfl_xor(mx, 32));
    tm = fmaxf(tm, mx);

    if (__any(mx > m + 8.0f)){   // defer-max THR=8 (log2 units)
      const float mn = fmaxf(m, mx);
      const float s = exp2_fast(m - mn);
      l *= s; m = mn;
      float rs[4];
#pragma unroll
      for (int r = 0; r < 4; ++r)
        rs[r] = __shfl(s, (lc << 4) | (lc*4 + r), 64);
#pragma unroll
      for (int dt = 0; dt < 4; ++dt)
#pragma unroll
        for (int r = 0; r < 4; ++r) acc[dt][r] *= rs[r];
    }

    // P = exp2(sc - m); in-lane sum + 2 hops
    f32x4 ssum = {};
#pragma unroll
    for (int nt = 0; nt < 4; ++nt){
#pragma unroll
      for (int r = 0; r < 4; ++r) sc[nt][r] = exp2_fast(sc[nt][r] - m);
      ssum += sc[nt];
    }
    float s1 = (ssum[0] + ssum[1]) + (ssum[2] + ssum[3]);
    s1 += __shfl_xor(s1, 16);
    s1 += __shfl_xor(s1, 32);
    l += s1;

    // pack P -> per-wave swizzled LDS tile (row q=lr)
    char* pw = (char*)&sP[wid][0][0];
#pragma unroll
    for (int nt = 0; nt < 4; ++nt){
      int2 pk;
      pk.x = __builtin_bit_cast(int, __builtin_amdgcn_cvt_pkrtz(sc[nt][0], sc[nt][1]));
      pk.y = __builtin_bit_cast(int, __builtin_amdgcn_cvt_pkrtz(sc[nt][2], sc[nt][3]));
      *reinterpret_cast<int2*>(pw + lr*128 + ((nt*32 + lc*8) ^ swz)) = pk;
    }

    // PV A-fragment: row q=lr, k = kc*32 + lc*8 + j (same XOR as the writes)
    const half8 pa0 = *reinterpret_cast<const half8*>(pw + lr*128 + ((lc*16) ^ swz));
    const half8 pa1 = *reinterpret_cast<const half8*>(pw + lr*128 + ((64 + lc*16) ^ swz));

    asm volatile("s_waitcnt vmcnt(0)" ::: "memory");   // own V landed
    __builtin_amdgcn_sched_barrier(0);
    __builtin_amdgcn_s_barrier();           // all waves' V visible

    const char* vb = (const char*)&sV[0][0];
    __builtin_amdgcn_s_setprio(1);
#pragma unroll
    for (int dt = 0; dt < 4; ++dt){
#pragma unroll
      for (int kc = 0; kc < 2; ++kc){
        const half8 fv = *reinterpret_cast<const half8*>(
            vb + (dt*16 + lr)*128 + ((kc*64 + lc*16) ^ swz));
        acc[dt] = MFMA16(kc ? pa1 : pa0, fv, acc[dt]);
      }
    }
    __builtin_amdgcn_s_setprio(0);
  }

  // partial epilogue: undivided acc (fp16) + stats (f32)
#pragma unroll
  for (int dt = 0; dt < 4; ++dt)
#pragma unroll
    for (int r = 0; r < 4; ++r)
      Op[(wid*16 + lc*4 + r)*64 + dt*16 + lr] = (_Float16)acc[dt][r];
  if (lane < 16){
    Sp[wid*16 + lr] = m;
    Sp[64 + wid*16 + lr] = l;
    Sp[128 + wid*16 + lr] = tm;
  }
}

// ---------------- merge the two KV-halves (exact, ghost-preserving) ----------
__global__ __launch_bounds__(256) void attn_merge(
    const _Float16* __restrict__ Opart, const float* __restrict__ Spart,
    _Float16* __restrict__ Ao)
{
  const int id = blockIdx.x;            // 0..1023 = (bh, qt)
  const int bh = id >> 5, qt = id & 31;
  const int tid = threadIdx.x;
  const int row = tid >> 2, seg = tid & 3;
  const int p0 = (bh * 32 + qt) * 2, p1 = p0 + 1;
  const float* S1 = Spart + (size_t)p0 * 192;
  const float* S2 = Spart + (size_t)p1 * 192;
  const float m1 = S1[row], l1 = S1[64 + row], t1 = S1[128 + row];
  const float m2 = S2[row], l2 = S2[64 + row], t2 = S2[128 + row];
  const float M  = fmaxf(m1, m2);
  const float w1 = exp2_fast(m1 - M), w2 = exp2_fast(m2 - M);
  const float den = l1 * w1 + l2 * w2 + exp2_fast(fmaxf(t1, t2) - M);
  const float inv = 1.0f / den;
  const half8* O1 = reinterpret_cast<const half8*>(Opart + (size_t)p0 * 4096 + row * 64 + seg * 16);
  const half8* O2 = reinterpret_cast<const half8*>(Opart + (size_t)p1 * 4096 + row * 64 + seg * 16);
  const int b = bh >> 4, hh = bh & 15;
  const int q = qt * 64 + row;
  _Float16* dst = Ao + ((size_t)(b * S_LEN + q)) * E_DIM + hh * D_DIM + seg * 16;
#pragma unroll
  for (int v = 0; v < 2; ++v){
    const half8 a1 = O1[v], a2 = O2[v];
    half8 o;
#pragma unroll
    for (int j = 0; j < 8; ++j)
      o[j] = (_Float16)(((float)a1[j] * w1 + (float)a2[j] * w2) * inv);
    reinterpret_cast<half8*>(dst)[v] = o;
  }
}

// ---------------- launch ----------------
extern "C" void kernel_launch(void* const* d_in, const int* in_sizes, int n_in,
                              void* d_out, int out_size, void* d_ws, size_t ws_size,
                              hipStream_t stream){
  const float* X    = (const float*)d_in[0];
  const float* Wqkv = (const float*)d_in[1];
  const float* Wo   = (const float*)d_in[2];
  float* out = (float*)d_out;

  _Float16* w = (_Float16*)d_ws;
  size_t off = 0;
  auto alloc = [&](size_t n){ _Float16* p = w + off; off += n; return p; };
  const size_t ME   = (size_t)M_ROWS * E_DIM;
  const size_t WQ   = (size_t)N3 * E_DIM;
  const size_t WOsz = (size_t)E_DIM * E_DIM;
  const size_t QK   = (size_t)NBH * S_LEN * D_DIM;
  _Float16 *Xh = alloc(ME);
  _Float16 *Wqh = alloc(WQ);
  _Float16 *Woh = alloc(WOsz);
  _Float16 *Qh = alloc(QK), *Kh = alloc(QK), *Vth = alloc(QK);
  _Float16 *Ahalf = alloc(ME);
  _Float16 *Opart = alloc((size_t)2048 * 4096);
  _Float16 *Sraw  = alloc((size_t)2048 * 192 * 2);   // f32 stats region
  float* Spart = (float*)Sraw;

  prep_kernel<<<dim3(8192), 256, 0, stream>>>(X, Wqkv, Wo, Xh, Wqh, Woh);

  gemm97<1><<<dim3(N3/128, M_ROWS/128), 256, 0, stream>>>(
      Xh, Wqh, E_DIM, N3, nullptr, Qh, Kh, Vth);

  attn_partial<<<dim3(2048), 256, 0, stream>>>(Qh, Kh, Vth, Opart, Spart);
  attn_merge<<<dim3(1024), 256, 0, stream>>>(Opart, Spart, Ahalf);

  gemm64<<<dim3(E_DIM/128, M_ROWS/64), 256, 0, stream>>>(
      Ahalf, Woh, E_DIM, E_DIM, out);
}

// Round 25
// 111.124 us; speedup vs baseline: 1.0130x; 1.0130x over previous
//
#include <hip/hip_runtime.h>

typedef float    f32x4  __attribute__((ext_vector_type(4)));
typedef _Float16 half8  __attribute__((ext_vector_type(8)));
typedef _Float16 half4v __attribute__((ext_vector_type(4)));

#define MFMA16(a,b,c) __builtin_amdgcn_mfma_f32_16x16x32_f16(a,b,c,0,0,0)

__device__ __forceinline__ float exp2_fast(float x){
  float y; asm("v_exp_f32 %0, %1" : "=v"(y) : "v"(x)); return y;
}
// async global->LDS, 16B per lane; LDS dest is wave-uniform base + lane*16
__device__ __forceinline__ void gload_lds16(const _Float16* g, _Float16* l){
  __builtin_amdgcn_global_load_lds(
      (const __attribute__((address_space(1))) unsigned int*)(g),
      (__attribute__((address_space(3))) unsigned int*)(l),
      16, 0, 0);
}

#define S_LEN 2048
#define E_DIM 1024
#define H_NUM 16
#define D_DIM 64
#define NBH   32
#define M_ROWS 4096
#define N3    3072
#define LOG2E 1.44269504089f

// ---------------- fused prep: X cast + Wqkv^T + Wo^T in one dispatch --------
__global__ __launch_bounds__(256) void prep_kernel(
    const float* __restrict__ X, const float* __restrict__ Wqkv,
    const float* __restrict__ Wo,
    _Float16* __restrict__ Xh, _Float16* __restrict__ Wqh,
    _Float16* __restrict__ Woh)
{
  __shared__ float tile[32][33];
  const int blk = blockIdx.x, tid = threadIdx.x;
  if (blk < 4096){
    const int i = blk * 256 + tid;                  // i < 4096*256 = ME/4
    const float4 v = reinterpret_cast<const float4*>(X)[i];
    half4v h;
    h[0] = (_Float16)v.x; h[1] = (_Float16)v.y;
    h[2] = (_Float16)v.z; h[3] = (_Float16)v.w;
    *reinterpret_cast<half4v*>(&Xh[(size_t)i*4]) = h;
    return;
  }
  const float* in; _Float16* out; int R, C, bx, by;
  if (blk < 4096 + 3072){
    const int b2 = blk - 4096;
    in = Wqkv; out = Wqh; R = E_DIM; C = N3;
    bx = (b2 % 96) * 32; by = (b2 / 96) * 32;
  } else {
    const int b2 = blk - 7168;
    in = Wo; out = Woh; R = E_DIM; C = E_DIM;
    bx = (b2 % 32) * 32; by = (b2 / 32) * 32;
  }
  const int tx = tid & 31, ty = tid >> 5;           // 256 threads = 32x8
#pragma unroll
  for (int i = ty; i < 32; i += 8)
    tile[i][tx] = in[(size_t)(by + i) * C + bx + tx];
  __syncthreads();
#pragma unroll
  for (int i = ty; i < 32; i += 8)
    out[(size_t)(bx + i) * R + by + tx] = (_Float16)tile[tx][i];
}

// ---------------- fp16 GEMM (m97 structure + T2 swizzle), 128x128 ----------
// T1 XCD-chunked block remap: each XCD gets a contiguous run of block ids
// (4 m-rows x all n-tiles for GEMM1) so its A-panels stay L2-resident.
template<int EPI>
__global__ __launch_bounds__(256, 3) void gemm97(
    const _Float16* __restrict__ A, const _Float16* __restrict__ B,
    int Kdim, int Ndim, float* __restrict__ Cout,
    _Float16* __restrict__ qh, _Float16* __restrict__ kh, _Float16* __restrict__ vh)
{
  __shared__ __align__(16) _Float16 sA[128][64], sB[128][64];
  const int tid = threadIdx.x;
  const int nx = gridDim.x, nwg = nx * gridDim.y;
  int bidx = blockIdx.x, bidy = blockIdx.y;
  if ((nwg & 7) == 0){
    const int id = bidx + nx * bidy;
    const int nid = (id & 7) * (nwg >> 3) + (id >> 3);   // bijective: nwg%8==0
    bidx = nid % nx; bidy = nid / nx;
  }
  const int m0 = bidy * 128, n0 = bidx * 128;
  const int wid = tid >> 6, lane = tid & 63;
  const int wr = (wid >> 1) * 64, wc = (wid & 1) * 64;
  const int lr = lane & 15, lc = lane >> 4;
  const int ldrow = lane >> 3;                        // 0..7 within chunk
  const int ldcol = ((lane & 7) ^ ldrow) * 8;         // inverse-swizzled source col
  const int swz = (lr & 7) << 4;                      // byte XOR for reads

  f32x4 acc[4][4] = {};
  const int nK = Kdim >> 6;
  for (int ks = 0; ks < nK; ++ks){
    const int k0 = ks << 6;
#pragma unroll
    for (int cc = 0; cc < 4; ++cc){
      const int c = wid * 4 + cc;
      const int row = c * 8 + ldrow;
      gload_lds16(&A[(size_t)(m0 + row) * Kdim + k0 + ldcol], &sA[c*8][0]);
      gload_lds16(&B[(size_t)(n0 + row) * Kdim + k0 + ldcol], &sB[c*8][0]);
    }
    __syncthreads();
    const char* ab = (const char*)&sA[0][0];
    const char* bb = (const char*)&sB[0][0];
#pragma unroll
    for (int kk = 0; kk < 64; kk += 32){
      half8 fa[4], fb[4];
#pragma unroll
      for (int t = 0; t < 4; ++t){
        fa[t] = *reinterpret_cast<const half8*>(
            ab + (wr + t*16 + lr)*128 + ((kk*2 + lc*16) ^ swz));
        fb[t] = *reinterpret_cast<const half8*>(
            bb + (wc + t*16 + lr)*128 + ((kk*2 + lc*16) ^ swz));
      }
#pragma unroll
      for (int mt = 0; mt < 4; ++mt)
#pragma unroll
        for (int nt = 0; nt < 4; ++nt)
          acc[mt][nt] = MFMA16(fa[mt], fb[nt], acc[mt][nt]);
    }
    __syncthreads();
  }
#pragma unroll
  for (int mt = 0; mt < 4; ++mt)
#pragma unroll
    for (int nt = 0; nt < 4; ++nt)
#pragma unroll
      for (int r = 0; r < 4; ++r){
        const int m = m0 + wr + mt*16 + lc*4 + r;
        const int n = n0 + wc + nt*16 + lr;
        float v = acc[mt][nt][r];
        if (EPI == 0){
          Cout[(size_t)m * Ndim + n] = v;
        } else {
          const int t = n >> 10, rem = n & 1023, hh = rem >> 6, d = rem & 63;
          const int b = m >> 11, s = m & 2047;
          const int bh = b * H_NUM + hh;
          if (t == 0) v *= (0.125f * LOG2E);  // fold 1/sqrt(64) and log2(e) into Q
          size_t o;
          if (t == 2)  o = ((size_t)bh * D_DIM + d) * S_LEN + s;   // V transposed
          else         o = ((size_t)bh * S_LEN + s) * D_DIM + d;
          _Float16* ph = (t == 0) ? qh : (t == 1) ? kh : vh;
          ph[o] = (_Float16)v;
        }
      }
}

// ---------------- fp16 GEMM, 64x128 tile (occupancy variant for GEMM2) -----
// T1 XCD-chunked remap: Wo^T (2MB) becomes L2-resident per XCD.
__global__ __launch_bounds__(256, 4) void gemm64(
    const _Float16* __restrict__ A, const _Float16* __restrict__ B,
    int Kdim, int Ndim, float* __restrict__ Cout)
{
  __shared__ __align__(16) _Float16 sA[64][64], sB[128][64];
  const int tid = threadIdx.x;
  const int nx = gridDim.x, nwg = nx * gridDim.y;
  int bidx = blockIdx.x, bidy = blockIdx.y;
  if ((nwg & 7) == 0){
    const int id = bidx + nx * bidy;
    const int nid = (id & 7) * (nwg >> 3) + (id >> 3);   // bijective: nwg%8==0
    bidx = nid % nx; bidy = nid / nx;
  }
  const int m0 = bidy * 64, n0 = bidx * 128;
  const int wid = tid >> 6, lane = tid & 63;
  const int wr = (wid >> 1) * 32, wc = (wid & 1) * 64;
  const int lr = lane & 15, lc = lane >> 4;
  const int ldrow = lane >> 3;
  const int ldcol = ((lane & 7) ^ ldrow) * 8;
  const int swz = (lr & 7) << 4;

  f32x4 acc[2][4] = {};
  const int nK = Kdim >> 6;
  for (int ks = 0; ks < nK; ++ks){
    const int k0 = ks << 6;
#pragma unroll
    for (int cc = 0; cc < 2; ++cc){
      const int c = wid * 2 + cc;
      const int row = c * 8 + ldrow;
      gload_lds16(&A[(size_t)(m0 + row) * Kdim + k0 + ldcol], &sA[c*8][0]);
    }
#pragma unroll
    for (int cc = 0; cc < 4; ++cc){
      const int c = wid * 4 + cc;
      const int row = c * 8 + ldrow;
      gload_lds16(&B[(size_t)(n0 + row) * Kdim + k0 + ldcol], &sB[c*8][0]);
    }
    __syncthreads();
    const char* ab = (const char*)&sA[0][0];
    const char* bb = (const char*)&sB[0][0];
#pragma unroll
    for (int kk = 0; kk < 64; kk += 32){
      half8 fa[2], fb[4];
#pragma unroll
      for (int t = 0; t < 2; ++t)
        fa[t] = *reinterpret_cast<const half8*>(
            ab + (wr + t*16 + lr)*128 + ((kk*2 + lc*16) ^ swz));
#pragma unroll
      for (int t = 0; t < 4; ++t)
        fb[t] = *reinterpret_cast<const half8*>(
            bb + (wc + t*16 + lr)*128 + ((kk*2 + lc*16) ^ swz));
#pragma unroll
      for (int mt = 0; mt < 2; ++mt)
#pragma unroll
        for (int nt = 0; nt < 4; ++nt)
          acc[mt][nt] = MFMA16(fa[mt], fb[nt], acc[mt][nt]);
    }
    __syncthreads();
  }
#pragma unroll
  for (int mt = 0; mt < 2; ++mt)
#pragma unroll
    for (int nt = 0; nt < 4; ++nt)
#pragma unroll
      for (int r = 0; r < 4; ++r){
        const int m = m0 + wr + mt*16 + lc*4 + r;
        const int n = n0 + wc + nt*16 + lr;
        Cout[(size_t)m * Ndim + n] = acc[mt][nt][r];
      }
}

// ---------------- flash attention, KV-split partial, 6 blocks/CU (best) ------
// 2048 blocks: (bh, qt, half). Each processes KV tiles [t0,t1) of q-tile qt:
// half0 = [0, (qt+1)/2), half1 = [(qt+1)/2, qt+1) (has diagonal). <=16 iters.
// LDS = sK 8K + sV 8K + sP 8K = 24576 B -> 6 blocks/CU: TLP hides the per-iter
// staging latency (K,V single-buffered, staged at iteration top via DMA).
// Writes fp16 partial O (undivided acc) + f32 stats (m, l, tm) to workspace.
__global__ __launch_bounds__(256, 6) void attn_partial(
    const _Float16* __restrict__ Qh, const _Float16* __restrict__ Kh,
    const _Float16* __restrict__ Vth,
    _Float16* __restrict__ Opart, float* __restrict__ Spart)
{
  __shared__ __align__(16) _Float16 sK[64][64];      // 8192 B [kv][d]
  __shared__ __align__(16) _Float16 sV[64][64];      // 8192 B [d][kv]
  __shared__ __align__(16) _Float16 sP[4][16][64];   // 8192 B per-wave P
  const int tid = threadIdx.x, wid = tid >> 6, lane = tid & 63;
  const int id  = blockIdx.x;                  // 0..2047
  const int xcd = id & 7, seq = id >> 3;       // seq 0..255
  const int bh  = xcd + 8 * (seq & 3);
  const int rest = seq >> 2;                   // 0..63
  const int qt  = 31 - (rest >> 1);            // long blocks dispatch first
  const int half = rest & 1;
  const int h0 = (qt + 1) >> 1;
  const int t0 = half ? h0 : 0;
  const int t1 = half ? (qt + 1) : h0;
  const int q0 = qt * 64;
  const int lr = lane & 15, lc = lane >> 4;
  const int swz = (lr & 7) << 4;               // byte XOR for swizzled LDS accesses
  const size_t base = (size_t)bh * S_LEN * D_DIM;

  const int pidx = (bh * 32 + qt) * 2 + half;
  _Float16* Op = Opart + (size_t)pidx * 4096;
  float*    Sp = Spart + (size_t)pidx * 192;   // [3][64]

  if (t1 <= t0){                               // empty chunk (qt=0, half0)
#pragma unroll
    for (int dt = 0; dt < 4; ++dt)
#pragma unroll
      for (int r = 0; r < 4; ++r)
        Op[(wid*16 + lc*4 + r)*64 + dt*16 + lr] = (_Float16)0.f;
    if (lane < 16){
      Sp[wid*16 + lr] = -1e30f;
      Sp[64 + wid*16 + lr] = 0.f;
      Sp[128 + wid*16 + lr] = -1e30f;
    }
    return;
  }

  // staging geometry: wave w stages chunks {2w,2w+1} (8 rows each)
  const int lrow = lane >> 3;                       // 0..7
  const int cswz = ((lane & 7) ^ lrow) * 8;         // inverse-swizzled source col

  auto stage = [&](int t){
    const int kv0 = t * 64;
#pragma unroll
    for (int cc = 0; cc < 2; ++cc){
      const int ch = wid * 2 + cc;
      const int row = ch * 8 + lrow;
      gload_lds16(&Kh[base + (size_t)(kv0 + row) * D_DIM + cswz], &sK[ch*8][0]);
      gload_lds16(&Vth[base + (size_t)row * S_LEN + kv0 + cswz], &sV[ch*8][0]);
    }
  };

  // Q fragments (B-operand), hoisted; Q already scaled by log2e/8
  half8 fq[2];
  {
    const int qrow = q0 + wid*16 + lr;
#pragma unroll
    for (int kc = 0; kc < 2; ++kc)
      fq[kc] = *reinterpret_cast<const half8*>(&Qh[base + (size_t)qrow * 64 + kc*32 + lc*8]);
  }

  f32x4 acc[4] = {};
  float m = -1e30f, l = 0.f, tm = -1e30f;   // per-lane stats for q = lr

#pragma unroll 1
  for (int t = t0; t < t1; ++t){
    __syncthreads();                        // prior iteration's LDS reads done
    stage(t);
    __syncthreads();                        // drains vmcnt; staging visible

    // ST = K·Q^T: lane holds q=lr (col), k = nt*16 + lc*4 + r (row)
    const char* kb = (const char*)&sK[0][0];
    f32x4 sc[4];
    __builtin_amdgcn_s_setprio(1);
#pragma unroll
    for (int nt = 0; nt < 4; ++nt){
      f32x4 z = {};
#pragma unroll
      for (int kc = 0; kc < 2; ++kc){
        const half8 fk = *reinterpret_cast<const half8*>(
            kb + (nt*16 + lr)*128 + ((kc*64 + lc*16) ^ swz));
        z = MFMA16(fk, fq[kc], z);
      }
      sc[nt] = z;
    }
    __builtin_amdgcn_s_setprio(0);

    if (t == qt){   // diagonal: mask k > q
#pragma unroll
      for (int nt = 0; nt < 4; ++nt)
#pragma unroll
        for (int r = 0; r < 4; ++r)
          if (nt*16 + lc*4 + r > wid*16 + lr) sc[nt][r] = -1e30f;
    }

    // in-lane max over 16 + 2 cross-lane hops (lanes lr, lr+16, lr+32, lr+48)
    f32x4 a;
#pragma unroll
    for (int j = 0; j < 4; ++j)
      a[j] = fmaxf(fmaxf(sc[0][j], sc[1][j]), fmaxf(sc[2][j], sc[3][j]));
    float mx = fmaxf(fmaxf(a[0], a[1]), fmaxf(a[2], a[3]));
    mx = fmaxf(mx, __shfl_xor(mx, 16));
    mx = fmaxf(mx, __shfl_xor(mx, 32));
    tm = fmaxf(tm, mx);

    if (__any(mx > m + 8.0f)){   // defer-max THR=8 (log2 units)
      const float mn = fmaxf(m, mx);
      const float s = exp2_fast(m - mn);
      l *= s; m = mn;
      float rs[4];
#pragma unroll
      for (int r = 0; r < 4; ++r)
        rs[r] = __shfl(s, (lc << 4) | (lc*4 + r), 64);
#pragma unroll
      for (int dt = 0; dt < 4; ++dt)
#pragma unroll
        for (int r = 0; r < 4; ++r) acc[dt][r] *= rs[r];
    }

    // P = exp2(sc - m); in-lane sum + 2 hops
    f32x4 ssum = {};
#pragma unroll
    for (int nt = 0; nt < 4; ++nt){
#pragma unroll
      for (int r = 0; r < 4; ++r) sc[nt][r] = exp2_fast(sc[nt][r] - m);
      ssum += sc[nt];
    }
    float s1 = (ssum[0] + ssum[1]) + (ssum[2] + ssum[3]);
    s1 += __shfl_xor(s1, 16);
    s1 += __shfl_xor(s1, 32);
    l += s1;

    // pack P -> per-wave swizzled LDS tile (row q=lr)
    char* pw = (char*)&sP[wid][0][0];
#pragma unroll
    for (int nt = 0; nt < 4; ++nt){
      int2 pk;
      pk.x = __builtin_bit_cast(int, __builtin_amdgcn_cvt_pkrtz(sc[nt][0], sc[nt][1]));
      pk.y = __builtin_bit_cast(int, __builtin_amdgcn_cvt_pkrtz(sc[nt][2], sc[nt][3]));
      *reinterpret_cast<int2*>(pw + lr*128 + ((nt*32 + lc*8) ^ swz)) = pk;
    }

    // PV A-fragment: row q=lr, k = kc*32 + lc*8 + j (same XOR as the writes)
    const half8 pa0 = *reinterpret_cast<const half8*>(pw + lr*128 + ((lc*16) ^ swz));
    const half8 pa1 = *reinterpret_cast<const half8*>(pw + lr*128 + ((64 + lc*16) ^ swz));

    const char* vb = (const char*)&sV[0][0];
    __builtin_amdgcn_s_setprio(1);
#pragma unroll
    for (int dt = 0; dt < 4; ++dt){
#pragma unroll
      for (int kc = 0; kc < 2; ++kc){
        const half8 fv = *reinterpret_cast<const half8*>(
            vb + (dt*16 + lr)*128 + ((kc*64 + lc*16) ^ swz));
        acc[dt] = MFMA16(kc ? pa1 : pa0, fv, acc[dt]);
      }
    }
    __builtin_amdgcn_s_setprio(0);
  }

  // partial epilogue: undivided acc (fp16) + stats (f32)
#pragma unroll
  for (int dt = 0; dt < 4; ++dt)
#pragma unroll
    for (int r = 0; r < 4; ++r)
      Op[(wid*16 + lc*4 + r)*64 + dt*16 + lr] = (_Float16)acc[dt][r];
  if (lane < 16){
    Sp[wid*16 + lr] = m;
    Sp[64 + wid*16 + lr] = l;
    Sp[128 + wid*16 + lr] = tm;
  }
}

// ---------------- merge the two KV-halves (exact, ghost-preserving) ----------
__global__ __launch_bounds__(256) void attn_merge(
    const _Float16* __restrict__ Opart, const float* __restrict__ Spart,
    _Float16* __restrict__ Ao)
{
  const int id = blockIdx.x;            // 0..1023 = (bh, qt)
  const int bh = id >> 5, qt = id & 31;
  const int tid = threadIdx.x;
  const int row = tid >> 2, seg = tid & 3;
  const int p0 = (bh * 32 + qt) * 2, p1 = p0 + 1;
  const float* S1 = Spart + (size_t)p0 * 192;
  const float* S2 = Spart + (size_t)p1 * 192;
  const float m1 = S1[row], l1 = S1[64 + row], t1 = S1[128 + row];
  const float m2 = S2[row], l2 = S2[64 + row], t2 = S2[128 + row];
  const float M  = fmaxf(m1, m2);
  const float w1 = exp2_fast(m1 - M), w2 = exp2_fast(m2 - M);
  const float den = l1 * w1 + l2 * w2 + exp2_fast(fmaxf(t1, t2) - M);
  const float inv = 1.0f / den;
  const half8* O1 = reinterpret_cast<const half8*>(Opart + (size_t)p0 * 4096 + row * 64 + seg * 16);
  const half8* O2 = reinterpret_cast<const half8*>(Opart + (size_t)p1 * 4096 + row * 64 + seg * 16);
  const int b = bh >> 4, hh = bh & 15;
  const int q = qt * 64 + row;
  _Float16* dst = Ao + ((size_t)(b * S_LEN + q)) * E_DIM + hh * D_DIM + seg * 16;
#pragma unroll
  for (int v = 0; v < 2; ++v){
    const half8 a1 = O1[v], a2 = O2[v];
    half8 o;
#pragma unroll
    for (int j = 0; j < 8; ++j)
      o[j] = (_Float16)(((float)a1[j] * w1 + (float)a2[j] * w2) * inv);
    reinterpret_cast<half8*>(dst)[v] = o;
  }
}

// ---------------- launch ----------------
extern "C" void kernel_launch(void* const* d_in, const int* in_sizes, int n_in,
                              void* d_out, int out_size, void* d_ws, size_t ws_size,
                              hipStream_t stream){
  const float* X    = (const float*)d_in[0];
  const float* Wqkv = (const float*)d_in[1];
  const float* Wo   = (const float*)d_in[2];
  float* out = (float*)d_out;

  _Float16* w = (_Float16*)d_ws;
  size_t off = 0;
  auto alloc = [&](size_t n){ _Float16* p = w + off; off += n; return p; };
  const size_t ME   = (size_t)M_ROWS * E_DIM;
  const size_t WQ   = (size_t)N3 * E_DIM;
  const size_t WOsz = (size_t)E_DIM * E_DIM;
  const size_t QK   = (size_t)NBH * S_LEN * D_DIM;
  _Float16 *Xh = alloc(ME);
  _Float16 *Wqh = alloc(WQ);
  _Float16 *Woh = alloc(WOsz);
  _Float16 *Qh = alloc(QK), *Kh = alloc(QK), *Vth = alloc(QK);
  _Float16 *Ahalf = alloc(ME);
  _Float16 *Opart = alloc((size_t)2048 * 4096);
  _Float16 *Sraw  = alloc((size_t)2048 * 192 * 2);   // f32 stats region
  float* Spart = (float*)Sraw;

  prep_kernel<<<dim3(8192), 256, 0, stream>>>(X, Wqkv, Wo, Xh, Wqh, Woh);

  gemm97<1><<<dim3(N3/128, M_ROWS/128), 256, 0, stream>>>(
      Xh, Wqh, E_DIM, N3, nullptr, Qh, Kh, Vth);

  attn_partial<<<dim3(2048), 256, 0, stream>>>(Qh, Kh, Vth, Opart, Spart);
  attn_merge<<<dim3(1024), 256, 0, stream>>>(Opart, Spart, Ahalf);

  gemm64<<<dim3(E_DIM/128, M_ROWS/64), 256, 0, stream>>>(
      Ahalf, Woh, E_DIM, E_DIM, out);
}